// Round 9
// baseline (628.355 us; speedup 1.0000x reference)
//
#include <hip/hip_runtime.h>
#include <hip/hip_bf16.h>
#include <math.h>

typedef __bf16 bf16x8 __attribute__((ext_vector_type(8)));
typedef __bf16 bf16x4 __attribute__((ext_vector_type(4)));
typedef float f32x4 __attribute__((ext_vector_type(4)));
typedef float f32x2 __attribute__((ext_vector_type(2)));
typedef short s16x4 __attribute__((ext_vector_type(4)));

#define AS1 __attribute__((address_space(1)))
#define AS3 __attribute__((address_space(3)))

__device__ __forceinline__ void gll16(const __bf16* g, __bf16* l) {
    __builtin_amdgcn_global_load_lds((const AS1 unsigned int*)g,
                                     (AS3 unsigned int*)l, 16, 0, 0);
}

#define VMCNT(n) asm volatile("s_waitcnt vmcnt(" #n ")" ::: "memory")

#if __has_builtin(__builtin_amdgcn_exp2f)
#define EXP2(x) __builtin_amdgcn_exp2f(x)
#else
#define EXP2(x) __expf((x) * 0.69314718055994530942f)
#endif

// PV matmul with K=16 MFMA: B-operand layout (lane holds B[k=quad*4+j][q=l15])
// matches the QK^T score output layout exactly -> no cross-lane shuffle.
__device__ __forceinline__ f32x4 mfma16x16(bf16x4 a, bf16x4 b, f32x4 c) {
#if __has_builtin(__builtin_amdgcn_mfma_f32_16x16x16bf16_1k)
    union { bf16x4 h; s16x4 s; } ua, ub;
    ua.h = a; ub.h = b;
    return __builtin_amdgcn_mfma_f32_16x16x16bf16_1k(ua.s, ub.s, c, 0, 0, 0);
#else
    f32x4 d = c;
    asm volatile("v_mfma_f32_16x16x16_bf16 %0, %1, %2, %0"
                 : "+v"(d) : "v"(a), "v"(b));
    return d;
#endif
}

// ---------------------------------------------------------------------------
// All 6 weight transposes (fp32 [K,N] -> bf16 [N,K]) in one launch.
// ---------------------------------------------------------------------------
__global__ __launch_bounds__(256) void transpose_all(
    const float* __restrict__ Wq, const float* __restrict__ Wk,
    const float* __restrict__ Wv, const float* __restrict__ Wo,
    const float* __restrict__ W1, const float* __restrict__ W2,
    __bf16* __restrict__ Wqt, __bf16* __restrict__ Wkt,
    __bf16* __restrict__ Wvt, __bf16* __restrict__ Wot,
    __bf16* __restrict__ W1t, __bf16* __restrict__ W2t) {
    int g = blockIdx.x;
    const float* W; __bf16* Wt; int K, N, kt, nt;
    if (g < 4096) {
        int mi = g >> 10, loc = g & 1023;
        K = 1024; N = 1024; kt = loc >> 5; nt = loc & 31;
        W  = mi == 0 ? Wq  : mi == 1 ? Wk  : mi == 2 ? Wv  : Wo;
        Wt = mi == 0 ? Wqt : mi == 1 ? Wkt : mi == 2 ? Wvt : Wot;
    } else if (g < 8192) {
        int loc = g - 4096; W = W1; Wt = W1t;
        K = 1024; N = 4096; kt = loc >> 7; nt = loc & 127;
    } else {
        int loc = g - 8192; W = W2; Wt = W2t;
        K = 4096; N = 1024; kt = loc >> 5; nt = loc & 31;
    }
    int k0 = kt * 32, n0 = nt * 32;
    __shared__ float tile[32][33];
    int tx = threadIdx.x & 31, ty = threadIdx.x >> 5;
    #pragma unroll
    for (int j = ty; j < 32; j += 8)
        tile[j][tx] = W[(size_t)(k0 + j) * N + n0 + tx];
    __syncthreads();
    #pragma unroll
    for (int j = ty; j < 32; j += 8)
        Wt[(size_t)(n0 + j) * K + k0 + tx] = (__bf16)tile[tx][j];
}

// ---------------------------------------------------------------------------
// Fused 3-way pre-norm.
// ---------------------------------------------------------------------------
__global__ __launch_bounds__(256) void ln3_kernel(
    const float* __restrict__ q, const float* __restrict__ k,
    const float* __restrict__ v,
    const float* __restrict__ g1, const float* __restrict__ b1,
    const float* __restrict__ g2, const float* __restrict__ b2,
    float* __restrict__ qln, __bf16* __restrict__ qbf,
    __bf16* __restrict__ kbf, __bf16* __restrict__ vbf) {
    const int E = 1024;
    int which = blockIdx.y;
    const float* x = which == 0 ? q : which == 1 ? k : v;
    const float* g = which == 0 ? g1 : g2;
    const float* bb = which == 0 ? b1 : b2;
    float* o32 = which == 0 ? qln : nullptr;
    __bf16* obf = which == 0 ? qbf : which == 1 ? kbf : vbf;

    size_t row = blockIdx.x;
    int t = threadIdx.x;
    float4 val = ((const float4*)(x + row * E))[t];
    float s  = val.x + val.y + val.z + val.w;
    float s2 = val.x * val.x + val.y * val.y + val.z * val.z + val.w * val.w;
    #pragma unroll
    for (int off = 32; off >= 1; off >>= 1) {
        s  += __shfl_down(s, off);
        s2 += __shfl_down(s2, off);
    }
    __shared__ float red[2][4];
    int wid = t >> 6, lane = t & 63;
    if (lane == 0) { red[0][wid] = s; red[1][wid] = s2; }
    __syncthreads();
    if (t == 0) {
        float S1 = red[0][0] + red[0][1] + red[0][2] + red[0][3];
        float S2 = red[1][0] + red[1][1] + red[1][2] + red[1][3];
        float mean = S1 / E;
        float var  = S2 / E - mean * mean;
        red[0][0] = mean;
        red[1][0] = 1.0f / sqrtf(var + 1e-5f);
    }
    __syncthreads();
    float mean = red[0][0], rstd = red[1][0];
    float4 gv = ((const float4*)g)[t];
    float4 bv = ((const float4*)bb)[t];
    float y0 = (val.x - mean) * rstd * gv.x + bv.x;
    float y1 = (val.y - mean) * rstd * gv.y + bv.y;
    float y2 = (val.z - mean) * rstd * gv.z + bv.z;
    float y3 = (val.w - mean) * rstd * gv.w + bv.w;
    if (o32) ((float4*)(o32 + row * E))[t] = make_float4(y0, y1, y2, y3);
    bf16x4 o;
    o[0] = (__bf16)y0; o[1] = (__bf16)y1; o[2] = (__bf16)y2; o[3] = (__bf16)y3;
    ((bf16x4*)(obf + row * E))[t] = o;
}

// single-input LN (final norm), bf16 out
__global__ __launch_bounds__(256) void ln_kernel(const float* __restrict__ x,
                                                 const float* __restrict__ g,
                                                 const float* __restrict__ bb,
                                                 __bf16* __restrict__ outbf) {
    const int E = 1024;
    size_t row = blockIdx.x;
    int t = threadIdx.x;
    float4 v = ((const float4*)(x + row * E))[t];
    float s  = v.x + v.y + v.z + v.w;
    float s2 = v.x * v.x + v.y * v.y + v.z * v.z + v.w * v.w;
    #pragma unroll
    for (int off = 32; off >= 1; off >>= 1) {
        s  += __shfl_down(s, off);
        s2 += __shfl_down(s2, off);
    }
    __shared__ float red[2][4];
    int wid = t >> 6, lane = t & 63;
    if (lane == 0) { red[0][wid] = s; red[1][wid] = s2; }
    __syncthreads();
    if (t == 0) {
        float S1 = red[0][0] + red[0][1] + red[0][2] + red[0][3];
        float S2 = red[1][0] + red[1][1] + red[1][2] + red[1][3];
        float mean = S1 / E;
        float var  = S2 / E - mean * mean;
        red[0][0] = mean;
        red[1][0] = 1.0f / sqrtf(var + 1e-5f);
    }
    __syncthreads();
    float mean = red[0][0], rstd = red[1][0];
    float4 gv = ((const float4*)g)[t];
    float4 bv = ((const float4*)bb)[t];
    bf16x4 o;
    o[0] = (__bf16)((v.x - mean) * rstd * gv.x + bv.x);
    o[1] = (__bf16)((v.y - mean) * rstd * gv.y + bv.y);
    o[2] = (__bf16)((v.z - mean) * rstd * gv.z + bv.z);
    o[3] = (__bf16)((v.w - mean) * rstd * gv.w + bv.w);
    ((bf16x4*)(outbf + row * E))[t] = o;
}

// ---------------------------------------------------------------------------
// GEMM 256x256 tile, BK=64, 8 waves (2Mx4N), double-buffered LDS (128KB),
// 8-phase counted-vmcnt schedule (T3+T4): one half-tile (128x64) staged per
// phase INTO THE LIVE BUFFER, ordered so each region's overwrite issues only
// after its last read completed (B-halves last read P3/P7, A-halves P4/P8):
//   P1:B1[t+1]->b1  P2:A0[t+1]->b1  P3:A1[t+1]->b1  P4:B0[t+2]->b0 +vmcnt(2)
//   P5:B1[t+2]->b0  P6:A0[t+2]->b0  P7:A1[t+2]->b0  P8:B0[t+3]->b1 +vmcnt(2)
// vmcnt(2) (= only newest half-tile outstanding) guarantees the next-read
// tile fully landed; prefetch depth ~4-5 phases covers HBM latency.
// End-of-K handled by clamped tile indices (identical-content rewrites).
// ---------------------------------------------------------------------------
template <int EPI>
__global__ __launch_bounds__(512, 2) void gemm256(const __bf16* __restrict__ A,
                                                  const __bf16* __restrict__ A2,
                                                  const __bf16* __restrict__ Bt,
                                                  const __bf16* __restrict__ Bt2,
                                                  const float* __restrict__ bias,
                                                  const float* __restrict__ resid,
                                                  void* __restrict__ Cout,
                                                  int M, int N, int K,
                                                  int splitN, float scale) {
    __shared__ __bf16 As[2][256 * 64];
    __shared__ __bf16 Bs[2][256 * 64];
    int tid  = threadIdx.x;
    int lane = tid & 63, wid = tid >> 6;          // 8 waves
    int quad = lane >> 4, l15 = lane & 15;
    int waveM = wid >> 2, waveN = wid & 3;        // 2 x 4

    int GX = N >> 8;
    int id = blockIdx.x;
    int x8 = id & 7, tt = id >> 3;
    size_t rowBase = (size_t)((tt / GX) * 8 + x8) * 256;
    size_t colBase = (size_t)(tt % GX) * 256;

    const __bf16* Ap = A; const __bf16* Bp = Bt;
    size_t colLoc = colBase;
    float sc = scale;
    if ((int)colBase >= splitN) { Ap = A2; Bp = Bt2; colLoc = colBase - splitN; sc = 1.0f; }

    int lrow8  = lane >> 3;
    int lchunk = (lane & 7) ^ lrow8;              // inverse-swizzled source
    // half-tile staging bases: wave w covers rows h*128 + w*8 + {0,64} + (l>>3)
    const __bf16* AgH = Ap + (rowBase + wid * 8 + lrow8) * (size_t)K + lchunk * 8;
    const __bf16* BgH = Bp + (colLoc  + wid * 8 + lrow8) * (size_t)K + lchunk * 8;

#define STAGE_A256(buf, h, kt) do { \
    gll16(AgH + (size_t)((h) * 128) * K + (size_t)(kt) * 64,      &As[buf][((h) * 128 + wid * 8) * 64]); \
    gll16(AgH + (size_t)((h) * 128 + 64) * K + (size_t)(kt) * 64, &As[buf][((h) * 128 + wid * 8 + 64) * 64]); \
} while (0)
#define STAGE_B256(buf, h, kt) do { \
    gll16(BgH + (size_t)((h) * 128) * K + (size_t)(kt) * 64,      &Bs[buf][((h) * 128 + wid * 8) * 64]); \
    gll16(BgH + (size_t)((h) * 128 + 64) * K + (size_t)(kt) * 64, &Bs[buf][((h) * 128 + wid * 8 + 64) * 64]); \
} while (0)

    f32x4 acc[8][4] = {};
    int swz = l15 & 7;
    int nsteps = K >> 6;          // 16 or 64 (even)

    // prologue: tile0 (all 4 halves) -> buf0; tile1 B0 -> buf1
    STAGE_B256(0, 0, 0); STAGE_B256(0, 1, 0);
    STAGE_A256(0, 0, 0); STAGE_A256(0, 1, 0);
    STAGE_B256(1, 0, 1);
    VMCNT(2);
    __builtin_amdgcn_s_barrier();

    bf16x8 af[4], bfr[4];
    int p0 = (quad ^ swz) * 8;
    int p1 = ((4 + quad) ^ swz) * 8;

#define RD_B(buf, p) { _Pragma("unroll") \
    for (int ni = 0; ni < 4; ni++) \
        bfr[ni] = *(const bf16x8*)&Bs[buf][(waveN * 64 + ni * 16 + l15) * 64 + (p)]; }
#define RD_A(buf, mo, p) { _Pragma("unroll") \
    for (int mi = 0; mi < 4; mi++) \
        af[mi] = *(const bf16x8*)&As[buf][(waveM * 128 + ((mo) + mi) * 16 + l15) * 64 + (p)]; }
#define DO_MFMA(ao) { __builtin_amdgcn_s_barrier(); __builtin_amdgcn_s_setprio(1); \
    _Pragma("unroll") for (int mi = 0; mi < 4; mi++) \
    _Pragma("unroll") for (int ni = 0; ni < 4; ni++) \
        acc[(ao) + mi][ni] = __builtin_amdgcn_mfma_f32_16x16x32_bf16( \
            bfr[ni], af[mi], acc[(ao) + mi][ni], 0, 0, 0); \
    __builtin_amdgcn_s_setprio(0); __builtin_amdgcn_s_barrier(); }

    for (int T = 0; T < nsteps; T += 2) {
        int S2 = T + 2 < nsteps ? T + 2 : nsteps - 1;
        int S3 = T + 3 < nsteps ? T + 3 : nsteps - 1;
        // ---- P1: tile T (buf0) ks0 mi0-3; stage B1[T+1]->buf1
        RD_B(0, p0); RD_A(0, 0, p0);
        STAGE_B256(1, 1, T + 1);
        DO_MFMA(0);
        // ---- P2: ks0 mi4-7; stage A0[T+1]->buf1
        RD_A(0, 4, p0);
        STAGE_A256(1, 0, T + 1);
        DO_MFMA(4);
        // ---- P3: ks1 mi0-3; stage A1[T+1]->buf1
        RD_B(0, p1); RD_A(0, 0, p1);
        STAGE_A256(1, 1, T + 1);
        DO_MFMA(0);
        // ---- P4: ks1 mi4-7; stage B0[T+2]->buf0; vmcnt(2)
        RD_A(0, 4, p1);
        STAGE_B256(0, 0, S2);
        VMCNT(2);
        DO_MFMA(4);
        // ---- P5: tile T+1 (buf1) ks0 mi0-3; stage B1[T+2]->buf0
        RD_B(1, p0); RD_A(1, 0, p0);
        STAGE_B256(0, 1, S2);
        DO_MFMA(0);
        // ---- P6: ks0 mi4-7; stage A0[T+2]->buf0
        RD_A(1, 4, p0);
        STAGE_A256(0, 0, S2);
        DO_MFMA(4);
        // ---- P7: ks1 mi0-3; stage A1[T+2]->buf0
        RD_B(1, p1); RD_A(1, 0, p1);
        STAGE_A256(0, 1, S2);
        DO_MFMA(0);
        // ---- P8: ks1 mi4-7; stage B0[T+3]->buf1; vmcnt(2)
        RD_A(1, 4, p1);
        STAGE_B256(1, 0, S3);
        VMCNT(2);
        DO_MFMA(4);
    }
#undef RD_B
#undef RD_A
#undef DO_MFMA
#undef STAGE_A256
#undef STAGE_B256

    #pragma unroll
    for (int mi = 0; mi < 8; mi++)
    #pragma unroll
    for (int ni = 0; ni < 4; ni++) {
        size_t row = rowBase + waveM * 128 + mi * 16 + l15;
        size_t col = colBase + waveN * 64 + ni * 16 + quad * 4;
        f32x4 v = acc[mi][ni];
        if (EPI == 1) {
            float4 b4 = *(const float4*)&bias[col];
            float4 r4 = *(const float4*)&resid[row * N + col];
            float4 o;
            o.x = v[0] + b4.x + r4.x; o.y = v[1] + b4.y + r4.y;
            o.z = v[2] + b4.z + r4.z; o.w = v[3] + b4.w + r4.w;
            *(float4*)&((float*)Cout)[row * N + col] = o;
        } else if (EPI == 2) {
            float4 b4 = *(const float4*)&bias[col];
            bf16x4 pk;
            #pragma unroll
            for (int r = 0; r < 4; r++) {
                float t2 = v[r] + ((const float*)&b4)[r];
                pk[r] = (__bf16)(0.5f * t2 * (1.0f + erff(t2 * 0.70710678118654752f)));
            }
            *(bf16x4*)&((__bf16*)Cout)[row * N + col] = pk;
        } else {
            bf16x4 pk;
            #pragma unroll
            for (int r = 0; r < 4; r++) pk[r] = (__bf16)(v[r] * sc);
            *(bf16x4*)&((__bf16*)Cout)[row * N + col] = pk;
        }
    }
}

// ---------------------------------------------------------------------------
// GEMM 256x128 tile, BK=64, 8 waves (4Mx2N), TRIPLE-buffered LDS (144KB):
// stage tile T+2 into buf (T+2)%3 (holds fully-read tile T-1 -> no WAR)
// during tile T's two phases (A in P1, B in P2); vmcnt(6) once per K-tile
// guarantees tile T+1 landed before its reads. 2-K-tile prefetch depth.
// ---------------------------------------------------------------------------
template <int EPI>
__global__ __launch_bounds__(512, 2) void gemm256x128(const __bf16* __restrict__ A,
                                                      const __bf16* __restrict__ Bt,
                                                      const float* __restrict__ bias,
                                                      const float* __restrict__ resid,
                                                      void* __restrict__ Cout,
                                                      int M, int N, int K,
                                                      float scale) {
    __shared__ __bf16 As[3][256 * 64];   // 96 KB
    __shared__ __bf16 Bs[3][128 * 64];   // 48 KB
    int tid  = threadIdx.x;
    int lane = tid & 63, wid = tid >> 6;          // 8 waves
    int quad = lane >> 4, l15 = lane & 15;
    int waveM = wid >> 1, waveN = wid & 1;        // 4 x 2

    int GX = N >> 7;
    int id = blockIdx.x;
    int x8 = id & 7, tt = id >> 3;
    size_t rowBase = (size_t)((tt / GX) * 8 + x8) * 256;
    size_t colBase = (size_t)(tt % GX) * 128;

    int lrow8  = lane >> 3;
    int lchunk = (lane & 7) ^ lrow8;              // inverse-swizzled source
    const __bf16* Ag0 = A  + (rowBase + wid * 32 + lrow8) * (size_t)K + lchunk * 8;
    const __bf16* Bg0 = Bt + (colBase + wid * 16 + lrow8) * (size_t)K + lchunk * 8;
    int ldsA = (wid * 32) * 64;                   // wave stages 32 A-rows
    int ldsB = (wid * 16) * 64;                   // wave stages 16 B-rows

#define STAGE_A4(buf, kt) { _Pragma("unroll") \
    for (int i = 0; i < 4; i++) \
        gll16(Ag0 + (size_t)i * 8 * K + (size_t)(kt) * 64, &As[buf][ldsA + i * 512]); }
#define STAGE_B2(buf, kt) { _Pragma("unroll") \
    for (int i = 0; i < 2; i++) \
        gll16(Bg0 + (size_t)i * 8 * K + (size_t)(kt) * 64, &Bs[buf][ldsB + i * 512]); }

    f32x4 acc[4][4] = {};
    int swz = l15 & 7;
    int nsteps = K >> 6;

    // prologue: tile0 -> buf0, tile1 -> buf1 (tile0 landed; tile1 may fly)
    STAGE_A4(0, 0); STAGE_B2(0, 0);
    STAGE_A4(1, 1); STAGE_B2(1, 1);
    VMCNT(6);
    __builtin_amdgcn_s_barrier();

    bf16x8 af[4], bfr[4];
    int p0 = (quad ^ swz) * 8;
    int p1 = ((4 + quad) ^ swz) * 8;

    int cb = 0;
    for (int T = 0; T < nsteps; T++) {
        int nb = cb + 2; if (nb >= 3) nb -= 3;
        int S = T + 2 < nsteps ? T + 2 : nsteps - 1;
        const __bf16* Asb = &As[cb][0];
        const __bf16* Bsb = &Bs[cb][0];

        // ---- P1: ks0; stage A[S]->nb ----
        #pragma unroll
        for (int ni = 0; ni < 4; ni++)
            bfr[ni] = *(const bf16x8*)&Bsb[(waveN * 64 + ni * 16 + l15) * 64 + p0];
        #pragma unroll
        for (int mi = 0; mi < 4; mi++)
            af[mi] = *(const bf16x8*)&Asb[(waveM * 64 + mi * 16 + l15) * 64 + p0];
        STAGE_A4(nb, S);
        __builtin_amdgcn_s_barrier();
        __builtin_amdgcn_s_setprio(1);
        #pragma unroll
        for (int mi = 0; mi < 4; mi++)
            #pragma unroll
            for (int ni = 0; ni < 4; ni++)
                acc[mi][ni] = __builtin_amdgcn_mfma_f32_16x16x32_bf16(
                    bfr[ni], af[mi], acc[mi][ni], 0, 0, 0);
        __builtin_amdgcn_s_setprio(0);
        __builtin_amdgcn_s_barrier();

        // ---- P2: ks1; stage B[S]->nb; vmcnt(6) ----
        #pragma unroll
        for (int ni = 0; ni < 4; ni++)
            bfr[ni] = *(const bf16x8*)&Bsb[(waveN * 64 + ni * 16 + l15) * 64 + p1];
        #pragma unroll
        for (int mi = 0; mi < 4; mi++)
            af[mi] = *(const bf16x8*)&Asb[(waveM * 64 + mi * 16 + l15) * 64 + p1];
        STAGE_B2(nb, S);
        VMCNT(6);
        __builtin_amdgcn_s_barrier();
        __builtin_amdgcn_s_setprio(1);
        #pragma unroll
        for (int mi = 0; mi < 4; mi++)
            #pragma unroll
            for (int ni = 0; ni < 4; ni++)
                acc[mi][ni] = __builtin_amdgcn_mfma_f32_16x16x32_bf16(
                    bfr[ni], af[mi], acc[mi][ni], 0, 0, 0);
        __builtin_amdgcn_s_setprio(0);
        __builtin_amdgcn_s_barrier();

        cb = cb + 1 == 3 ? 0 : cb + 1;
    }
#undef STAGE_A4
#undef STAGE_B2

    #pragma unroll
    for (int mi = 0; mi < 4; mi++)
    #pragma unroll
    for (int ni = 0; ni < 4; ni++) {
        size_t row = rowBase + waveM * 64 + mi * 16 + l15;
        size_t col = colBase + waveN * 64 + ni * 16 + quad * 4;
        f32x4 v = acc[mi][ni];
        if (EPI == 1) {
            float4 b4 = *(const float4*)&bias[col];
            float4 r4 = *(const float4*)&resid[row * N + col];
            float4 o;
            o.x = v[0] + b4.x + r4.x; o.y = v[1] + b4.y + r4.y;
            o.z = v[2] + b4.z + r4.z; o.w = v[3] + b4.w + r4.w;
            *(float4*)&((float*)Cout)[row * N + col] = o;
        } else if (EPI == 2) {
            float4 b4 = *(const float4*)&bias[col];
            bf16x4 pk;
            #pragma unroll
            for (int r = 0; r < 4; r++) {
                float t2 = v[r] + ((const float*)&b4)[r];
                pk[r] = (__bf16)(0.5f * t2 * (1.0f + erff(t2 * 0.70710678118654752f)));
            }
            *(bf16x4*)&((__bf16*)Cout)[row * N + col] = pk;
        } else {
            bf16x4 pk;
            #pragma unroll
            for (int r = 0; r < 4; r++) pk[r] = (__bf16)(v[r] * scale);
            *(bf16x4*)&((__bf16*)Cout)[row * N + col] = pk;
        }
    }
}

// ---------------------------------------------------------------------------
// V projection GEMM (non-swapped MFMA) writing V^T [E, M], packed stores.
// ---------------------------------------------------------------------------
__global__ __launch_bounds__(256) void gemmV(const __bf16* __restrict__ A,
                                             const __bf16* __restrict__ Bt,
                                             __bf16* __restrict__ Cout,
                                             int M, int N, int K) {
    __shared__ __bf16 As[128 * 64];
    __shared__ __bf16 Bs[128 * 64];
    int tid  = threadIdx.x;
    int lane = tid & 63, wid = tid >> 6;
    int quad = lane >> 4, l15 = lane & 15;
    int waveM = wid >> 1, waveN = wid & 1;

    int GX = N >> 7;
    int id = blockIdx.x;
    int x8 = id & 7, t = id >> 3;
    size_t rowBase = (size_t)((t / GX) * 8 + x8) * 128;
    size_t colBase = (size_t)(t % GX) * 128;

    int lrow8  = lane >> 3;
    int lchunk = (lane & 7) ^ lrow8;
    const __bf16* Ag0 = A  + (rowBase + wid * 32 + lrow8) * (size_t)K + lchunk * 8;
    const __bf16* Bg0 = Bt + (colBase + wid * 32 + lrow8) * (size_t)K + lchunk * 8;
    __bf16* AsB = &As[(wid * 32) * 64];
    __bf16* BsB = &Bs[(wid * 32) * 64];

    f32x4 acc[4][4] = {};
    int swz = l15 & 7;

    for (int kb = 0; kb < K; kb += 64) {
        __syncthreads();
        #pragma unroll
        for (int i = 0; i < 4; i++) {
            gll16(Ag0 + (size_t)i * 8 * K + kb, AsB + i * 512);
            gll16(Bg0 + (size_t)i * 8 * K + kb, BsB + i * 512);
        }
        __syncthreads();
        #pragma unroll
        for (int ks = 0; ks < 2; ks++) {
            int p = ((ks * 4 + quad) ^ swz) * 8;
            bf16x8 af[4], bfr[4];
            #pragma unroll
            for (int mi = 0; mi < 4; mi++)
                af[mi] = *(const bf16x8*)&As[(waveM * 64 + mi * 16 + l15) * 64 + p];
            #pragma unroll
            for (int ni = 0; ni < 4; ni++)
                bfr[ni] = *(const bf16x8*)&Bs[(waveN * 64 + ni * 16 + l15) * 64 + p];
            #pragma unroll
            for (int mi = 0; mi < 4; mi++)
                #pragma unroll
                for (int ni = 0; ni < 4; ni++)
                    acc[mi][ni] = __builtin_amdgcn_mfma_f32_16x16x32_bf16(
                        af[mi], bfr[ni], acc[mi][ni], 0, 0, 0);
        }
    }

    #pragma unroll
    for (int mi = 0; mi < 4; mi++)
    #pragma unroll
    for (int ni = 0; ni < 4; ni++) {
        size_t col = colBase + waveN * 64 + ni * 16 + l15;        // dim in E
        size_t m0  = rowBase + waveM * 64 + mi * 16 + quad * 4;   // token
        bf16x4 pk;
        #pragma unroll
        for (int r = 0; r < 4; r++) pk[r] = (__bf16)acc[mi][ni][r];
        *(bf16x4*)&Cout[col * M + m0] = pk;
    }
}

// ---------------------------------------------------------------------------
// Flash attention, transposed-score formulation, 512 threads (8 waves).
// Each wave owns 32 q-rows (2 groups of 16). PV uses 16x16x16 MFMA.
// ---------------------------------------------------------------------------
__global__ __launch_bounds__(512, 4) void attn_kernel(const __bf16* __restrict__ QK,
                                                      const __bf16* __restrict__ Vt,
                                                      const int* __restrict__ mask,
                                                      __bf16* __restrict__ Out) {
    const int S = 2048, E = 1024, E2 = 2048, M = 8192;
    int qt = blockIdx.x, bh = blockIdx.y;
    int b = bh >> 4, h = bh & 15;
    int q0 = qt * 256;
    int tid = threadIdx.x, lane = tid & 63, wid = tid >> 6;  // wid 0..7
    int quad = lane >> 4, l15 = lane & 15;

    __shared__ __bf16 Ks[2][4096];
    __shared__ __bf16 Vs[2][4096];

    bf16x8 aq[2][2];
    #pragma unroll
    for (int g = 0; g < 2; g++)
    #pragma unroll
    for (int hh = 0; hh < 2; hh++) {
        size_t row = (size_t)(b * S + q0 + wid * 32 + g * 16 + l15);
        aq[g][hh] = *(const bf16x8*)(QK + row * E2 + h * 64 + hh * 32 + quad * 8);
    }

    int lrow8  = lane >> 3;
    int lchunk = (lane & 7) ^ lrow8;
    const __bf16* Kg0 = QK + (size_t)(b * S + wid * 8 + lrow8) * E2 + 1024 + h * 64 + lchunk * 8;

    // V reg-staging: thread (rv, cv) loads global 16B chunk cv of V^T row rv.
    int rv = tid >> 3, cv = tid & 7;
    const __bf16* Vg0 = Vt + (size_t)(h * 64 + rv) * M + b * S + cv * 8;
    int c0   = ((cv & 1) << 2) + (cv >> 2);
    int lowb = (cv >> 1) & 1;
    int sv   = rv & 7;
    int wo0  = rv * 64 + ((c0 ^ sv) << 3) + (lowb << 2);
    int wo1  = rv * 64 + (((c0 + 2) ^ sv) << 3) + (lowb << 2);

    int swz = l15 & 7;

    f32x4 accO[2][4] = {};
    f32x2 acc2[2] = {};

    bf16x8 vreg = *(const bf16x8*)(Vg0);
    gll16(Kg0, &Ks[0][wid * 512]);
    *(bf16x4*)&Vs[0][wo0] = __builtin_shufflevector(vreg, vreg, 0, 1, 2, 3);
    *(bf16x4*)&Vs[0][wo1] = __builtin_shufflevector(vreg, vreg, 4, 5, 6, 7);
    __syncthreads();

    for (int kt = 0; kt < S / 64; kt++) {
        int k0 = kt * 64;
        int buf = kt & 1;
        if (kt + 1 < S / 64) {
            vreg = *(const bf16x8*)(Vg0 + k0 + 64);            // issue early (T14)
            gll16(Kg0 + (size_t)(k0 + 64) * E2, &Ks[buf ^ 1][wid * 512]);
        }
        const __bf16* Ksb = &Ks[buf][0];
        const __bf16* Vsb = &Vs[buf][0];

        bf16x4 pb[2][4];
        #pragma unroll
        for (int nt = 0; nt < 4; nt++) {
            bf16x8 a0 = *(const bf16x8*)&Ksb[(nt * 16 + l15) * 64 + ((quad) ^ swz) * 8];
            bf16x8 a1 = *(const bf16x8*)&Ksb[(nt * 16 + l15) * 64 + ((4 + quad) ^ swz) * 8];
            int4 mz = *(const int4*)&mask[b * S + k0 + nt * 16 + quad * 4];
            #pragma unroll
            for (int g = 0; g < 2; g++) {
                f32x4 a = {};
                a = __builtin_amdgcn_mfma_f32_16x16x32_bf16(a0, aq[g][0], a, 0, 0, 0);
                a = __builtin_amdgcn_mfma_f32_16x16x32_bf16(a1, aq[g][1], a, 0, 0, 0);
                float p0 = mz.x ? EXP2(a[0]) : 0.f;
                float p1 = mz.y ? EXP2(a[1]) : 0.f;
                float p2 = mz.z ? EXP2(a[2]) : 0.f;
                float p3 = mz.w ? EXP2(a[3]) : 0.f;
                f32x2 t01; t01[0] = p0; t01[1] = p1;
                f32x2 t23; t23[0] = p2; t23[1] = p3;
                acc2[g] += t01 + t23;
                bf16x4 pk;
                pk[0] = (__bf16)p0; pk[1] = (__bf16)p1;
                pk[2] = (__bf16)p2; pk[3] = (__bf16)p3;
                pb[g][nt] = pk;
            }
        }

        // PV: 2x b128 per dt; halves are nt fragments, shared by both groups.
        #pragma unroll
        for (int dt = 0; dt < 4; dt++) {
            const __bf16* vrow = &Vsb[(dt * 16 + l15) * 64];
            bf16x8 vv0 = *(const bf16x8*)&vrow[((quad * 2 + 0) ^ swz) * 8];
            bf16x8 vv1 = *(const bf16x8*)&vrow[((quad * 2 + 1) ^ swz) * 8];
            bf16x4 h00 = __builtin_shufflevector(vv0, vv0, 0, 1, 2, 3);
            bf16x4 h01 = __builtin_shufflevector(vv0, vv0, 4, 5, 6, 7);
            bf16x4 h10 = __builtin_shufflevector(vv1, vv1, 0, 1, 2, 3);
            bf16x4 h11 = __builtin_shufflevector(vv1, vv1, 4, 5, 6, 7);
            #pragma unroll
            for (int g = 0; g < 2; g++) {
                accO[g][dt] = mfma16x16(h00, pb[g][0], accO[g][dt]);
                accO[g][dt] = mfma16x16(h01, pb[g][1], accO[g][dt]);
                accO[g][dt] = mfma16x16(h10, pb[g][2], accO[g][dt]);
                accO[g][dt] = mfma16x16(h11, pb[g][3], accO[g][dt]);
            }
        }

        if (kt + 1 < S / 64) {
            // write-late half of the async stage (vmcnt wait lands here)
            *(bf16x4*)&Vs[buf ^ 1][wo0] = __builtin_shufflevector(vreg, vreg, 0, 1, 2, 3);
            *(bf16x4*)&Vs[buf ^ 1][wo1] = __builtin_shufflevector(vreg, vreg, 4, 5, 6, 7);
        }
        __syncthreads();
    }

    #pragma unroll
    for (int g = 0; g < 2; g++) {
        float l = acc2[g][0] + acc2[g][1];
        l += __shfl_xor(l, 16, 64);
        l += __shfl_xor(l, 32, 64);
        float inv = 1.0f / l;
        #pragma unroll
        for (int dt = 0; dt < 4; dt++) {
            size_t row = (size_t)(b * S + q0 + wid * 32 + g * 16 + l15);
            bf16x4 pk;
            #pragma unroll
            for (int r = 0; r < 4; r++) pk[r] = (__bf16)(accO[g][dt][r] * inv);
            *(bf16x4*)&Out[row * E + h * 64 + dt * 16 + quad * 4] = pk;
        }
    }
}

// ---------------------------------------------------------------------------
// Launch
// ---------------------------------------------------------------------------
extern "C" void kernel_launch(void* const* d_in, const int* in_sizes, int n_in,
                              void* d_out, int out_size, void* d_ws, size_t ws_size,
                              hipStream_t stream) {
    const int Bb = 4, S = 2048, E = 1024, FF = 4096;
    const int M = Bb * S;  // 8192

    const float* value = (const float*)d_in[0];
    const float* key   = (const float*)d_in[1];
    const float* query = (const float*)d_in[2];
    const int*   mask  = (const int*)d_in[3];
    const float* Wv    = (const float*)d_in[4];
    const float* Wk    = (const float*)d_in[5];
    const float* Wq    = (const float*)d_in[6];
    const float* Wo    = (const float*)d_in[7];
    const float* bo    = (const float*)d_in[8];
    const float* ln1_g = (const float*)d_in[9];
    const float* ln1_b = (const float*)d_in[10];
    const float* ln2_g = (const float*)d_in[11];
    const float* ln2_b = (const float*)d_in[12];
    const float* lnf_g = (const float*)d_in[13];
    const float* lnf_b = (const float*)d_in[14];
    const float* W1    = (const float*)d_in[15];
    const float* b1    = (const float*)d_in[16];
    const float* W2    = (const float*)d_in[17];
    const float* b2    = (const float*)d_in[18];

    char* ws = (char*)d_ws;
    const size_t MB = 1024 * 1024;
    __bf16* Wqt = (__bf16*)(ws + 0 * MB);
    __bf16* Wkt = (__bf16*)(ws + 2 * MB);
    __bf16* Wvt = (__bf16*)(ws + 4 * MB);
    __bf16* Wot = (__bf16*)(ws + 6 * MB);
    __bf16* W1t = (__bf16*)(ws + 8 * MB);    // [FF, E]
    __bf16* W2t = (__bf16*)(ws + 16 * MB);   // [E, FF]
    __bf16* q_bf = (__bf16*)(ws + 24 * MB);
    __bf16* k_bf = (__bf16*)(ws + 40 * MB);
    __bf16* v_bf = (__bf16*)(ws + 56 * MB);
    __bf16* QKb  = (__bf16*)(ws + 72 * MB);  // [M, 2E]
    __bf16* Vtg  = (__bf16*)(ws + 104 * MB); // V^T [E, M]
    __bf16* attn = q_bf;
    __bf16* x_ln = k_bf;
    __bf16* h1   = v_bf;                     // [M, FF] 64MB
    float*  qln  = (float*)(ws + 120 * MB);
    float*  x32  = (float*)(ws + 152 * MB);

    transpose_all<<<12288, 256, 0, stream>>>(Wq, Wk, Wv, Wo, W1, W2,
                                             Wqt, Wkt, Wvt, Wot, W1t, W2t);

    ln3_kernel<<<dim3(M, 3), 256, 0, stream>>>(query, key, value,
                                               ln1_g, ln1_b, ln2_g, ln2_b,
                                               qln, q_bf, k_bf, v_bf);

    // merged Q|K projection -> QKb [M, 2E]; Q side scaled (1/8)*log2(e).
    // 256² 8-phase counted-vmcnt: grid 32*8 = 256.
    gemm256<0><<<256, 512, 0, stream>>>(
        q_bf, k_bf, Wqt, Wkt, nullptr, nullptr, QKb, M, 2 * E, E, E,
        0.125f * 1.44269504088896f);

    // V projection -> V^T [E, M]. grid 8*64 (128² kept: transposed epilogue).
    gemmV<<<8 * 64, 256, 0, stream>>>(v_bf, Wvt, Vtg, M, E, E);

    attn_kernel<<<dim3(S / 256, Bb * 16), 512, 0, stream>>>(QKb, Vtg, mask, attn);

    // out proj + bias + residual(qln) -> x32 (f32). 256x128 3-buffer.
    gemm256x128<1><<<256, 512, 0, stream>>>(
        attn, Wot, bo, qln, x32, M, E, E, 1.0f);

    ln_kernel<<<M, 256, 0, stream>>>(x32, lnf_g, lnf_b, x_ln);

    // FFN1: 256² 8-phase counted-vmcnt: grid 32*16 = 512.
    gemm256<2><<<512, 512, 0, stream>>>(
        x_ln, x_ln, W1t, W1t, b1, nullptr, h1, M, FF, E, FF, 1.0f);
    // FFN2: 256x128 3-buffer, K=4096. grid 256.
    gemm256x128<1><<<256, 512, 0, stream>>>(
        h1, W2t, b2, x32, (float*)d_out, M, E, FF, 1.0f);
}